// Round 19
// baseline (132.944 us; speedup 1.0000x reference)
//
#include <hip/hip_runtime.h>
#include <math.h>

#define NN 50000
#define NE 1000000
#define NH 64
#define NKEY 100000      // 2*NN combined key space (src | NN+dst)
#define SPAN 256         // keys per bucket
#define NBKT 391         // ceil(NKEY / SPAN)
#define CAP 6144         // bucket capacity (mean 5115 + 14 sigma)
#define CH 16            // LDS staging entries per bucket (pow2 for shift math)
#define BINB 512         // bin-duty blocks in bin_pass (proven at 512)
#define PACKB 256        // pack-duty blocks in bin_pass

typedef _Float16 f16;
typedef _Float16 f16x4 __attribute__((ext_vector_type(4)));
typedef _Float16 f16x8 __attribute__((ext_vector_type(8)));
typedef float f32x4 __attribute__((ext_vector_type(4)));

// ---------- binning helpers -------------------------------------------------
__device__ __forceinline__ void push_pair(int key, int val, int* cnt,
                                          unsigned* buf, int* gcnt,
                                          unsigned* __restrict__ pairs) {
    int b = key >> 8;
    unsigned pk = ((unsigned)val << 8) | (unsigned)(key & 255);
    int slot = atomicAdd(&cnt[b], 1);           // LDS atomic
    if (slot < CH) {
        buf[b * CH + slot] = pk;
    } else {                                     // rare overflow: direct path
        int g = atomicAdd(&gcnt[b], 1);
        if (g < CAP) pairs[(size_t)b * CAP + g] = pk;
    }
}

__device__ __forceinline__ void flush_coop(int* cnt, int* s_fc, int* s_g,
                                           unsigned* buf, int* gcnt,
                                           unsigned* __restrict__ pairs) {
    __syncthreads();
    int t = threadIdx.x;
    for (int b = t; b < NBKT; b += 256) {
        int fc = cnt[b]; if (fc > CH) fc = CH;
        s_fc[b] = fc;
        s_g[b] = (fc > 0) ? atomicAdd(&gcnt[b], fc) : 0;
    }
    __syncthreads();
    for (int i = t; i < NBKT * CH; i += 256) {
        int b = i >> 4, s = i & 15;              // CH == 16
        if (s < s_fc[b])
            pairs[(size_t)b * CAP + s_g[b] + s] = buf[i];
    }
    __syncthreads();
    for (int b = t; b < NBKT; b += 256) cnt[b] = 0;
    __syncthreads();
}

// ---------- pass 1: bin 2M (key,val) pairs; extra blocks do f16/weight pack -
__global__ __launch_bounds__(256) void bin_pass(
    const int* __restrict__ src, const int* __restrict__ dst,
    int* __restrict__ gcnt, unsigned* __restrict__ pairs,
    const float* __restrict__ X, f16* __restrict__ X16,
    const float* __restrict__ Ws, const float* __restrict__ Wn,
    const float* __restrict__ Qw, f16* __restrict__ wp) {
    if (blockIdx.x >= BINB) {
        // ---- pack duty: X -> f16 table, weights -> fragment-packed f16 ----
        int start = (blockIdx.x - BINB) * 256 + threadIdx.x;
        for (int i = start; i < NN * NH / 4; i += PACKB * 256) {
            float4 v = ((const float4*)X)[i];
            f16x4 o = {(f16)v.x, (f16)v.y, (f16)v.z, (f16)v.w};
            ((f16x4*)X16)[i] = o;
        }
        for (int i = start; i < 16384; i += PACKB * 256) {
            int m  = i >> 12;
            int kc = (i >> 11) & 1;
            int l  = (i >> 3) & 63;
            int e  = i & 7;
            int ct = (i >> 9) & 3;
            int k  = kc * 32 + (l >> 4) * 8 + e;
            int j  = ct * 16 + (l & 15);
            const float* W = (m == 0) ? Ws : (m == 1) ? Wn : (m == 2) ? Qw
                                                          : (Qw + 4096);
            wp[i] = (f16)W[k * 64 + j];
        }
        return;
    }
    __shared__ int cnt[NBKT];
    __shared__ int s_fc[NBKT];
    __shared__ int s_g[NBKT];
    __shared__ unsigned buf[NBKT * CH];
    for (int b = threadIdx.x; b < NBKT; b += 256) cnt[b] = 0;
    __syncthreads();
    int r = 0;
    for (int base = blockIdx.x * 256; base < NE; base += BINB * 256) {
        int e = base + threadIdx.x;
        if (e < NE) {
            int s = src[e], d = dst[e];
            push_pair(s, d, cnt, buf, gcnt, pairs);       // out-edge of s
            push_pair(NN + d, s, cnt, buf, gcnt, pairs);  // in-edge of d
        }
        if ((++r & 3) == 0) flush_coop(cnt, s_fc, s_g, buf, gcnt, pairs);
    }
    flush_coop(cnt, s_fc, s_g, buf, gcnt, pairs);
}

// ---------- pass 2: per-bucket counting sort + off/csr (scan folded in) -----
__global__ __launch_bounds__(512) void sort_pass(
    const unsigned* __restrict__ pairs, const int* __restrict__ gcnt,
    int* __restrict__ off, int* __restrict__ csr) {
    __shared__ int hist[SPAN];
    __shared__ int scn[SPAN];
    __shared__ int bsc[512];
    int k = blockIdx.x;
    int t = threadIdx.x;

    bsc[t] = (t < NBKT) ? gcnt[t] : 0;
    __syncthreads();
    for (int o = 1; o < 512; o <<= 1) {
        int u = (t >= o) ? bsc[t - o] : 0;
        __syncthreads();
        bsc[t] += u;
        __syncthreads();
    }
    int base = (k > 0) ? bsc[k - 1] : 0;
    int n = gcnt[k]; if (n > CAP) n = CAP;
    const unsigned* bp = pairs + (size_t)k * CAP;
    if (k == 0 && t == 0) off[NKEY] = 2 * NE;    // sentinel

    if (t < SPAN) hist[t] = 0;
    __syncthreads();
    for (int i = t; i < n; i += 512)
        atomicAdd(&hist[bp[i] & 255], 1);
    __syncthreads();
    if (t < SPAN) scn[t] = hist[t];
    __syncthreads();
    for (int o = 1; o < SPAN; o <<= 1) {
        int u = 0;
        if (t < SPAN && t >= o) u = scn[t - o];
        __syncthreads();
        if (t < SPAN) scn[t] += u;
        __syncthreads();
    }
    if (t < SPAN) {
        int ex = base + scn[t] - hist[t];   // absolute exclusive prefix
        int gk = k * SPAN + t;
        if (gk < NKEY) off[gk] = ex;
        scn[t] = ex;                        // reuse as cursor
    }
    __syncthreads();
    for (int i = t; i < n; i += 512) {
        unsigned p = bp[i];
        int pos = atomicAdd(&scn[p & 255], 1);   // LDS atomic
        csr[pos] = (int)(p >> 8);                // block-local global store
    }
}

// clamp gathered index (protects rocprof dispatch-replay from stale buffers)
__device__ __forceinline__ int cidx(int i) {
    return max(0, min(i, NN - 1));
}

__device__ __forceinline__ float4 f16x4_to_f32(f16x4 r) {
    float4 o; o.x = (float)r.x; o.y = (float)r.y;
    o.z = (float)r.z; o.w = (float)r.w; return o;
}
__device__ __forceinline__ float4 shfl_xor4(float4 v, int m) {
    float4 o;
    o.x = __shfl_xor(v.x, m, 64); o.y = __shfl_xor(v.y, m, 64);
    o.z = __shfl_xor(v.z, m, 64); o.w = __shfl_xor(v.w, m, 64);
    return o;
}

// ---------- pass 3: gather-mean, 16-lane-group rows (4 edges / load instr) --
// wave = node; lane l: cols 4q..4q+3 (q=l&15) of edge-stream g=l>>4.
__global__ __launch_bounds__(256) void gather_mean(
    const f16* __restrict__ X16, const int* __restrict__ off_dst,
    const int* __restrict__ csr, f16* __restrict__ M16) {
    int wid = (int)(((long long)blockIdx.x * blockDim.x + threadIdx.x) >> 6);
    int l = threadIdx.x & 63;
    int q = l & 15, g = l >> 4;
    if (wid >= NN) return;
    int e0 = off_dst[wid], e1 = off_dst[wid + 1];
    int deg = e1 - e0;
    const f16x4* Xq = (const f16x4*)(X16 + 4 * q);   // row base + col offset
    float4 s0 = {0,0,0,0}, s1 = {0,0,0,0}, s2 = {0,0,0,0}, s3 = {0,0,0,0};
    int Tf = deg >> 2;          // fully-valid slots (all 4 streams)
    int t = 0;
    for (; t + 4 <= Tf; t += 4) {
        int i0 = cidx(csr[e0 + 4 * (t + 0) + g]);
        int i1 = cidx(csr[e0 + 4 * (t + 1) + g]);
        int i2 = cidx(csr[e0 + 4 * (t + 2) + g]);
        int i3 = cidx(csr[e0 + 4 * (t + 3) + g]);
        float4 r0 = f16x4_to_f32(Xq[(size_t)i0 * 16]);
        float4 r1 = f16x4_to_f32(Xq[(size_t)i1 * 16]);
        float4 r2 = f16x4_to_f32(Xq[(size_t)i2 * 16]);
        float4 r3 = f16x4_to_f32(Xq[(size_t)i3 * 16]);
        s0.x += r0.x; s0.y += r0.y; s0.z += r0.z; s0.w += r0.w;
        s1.x += r1.x; s1.y += r1.y; s1.z += r1.z; s1.w += r1.w;
        s2.x += r2.x; s2.y += r2.y; s2.z += r2.z; s2.w += r2.w;
        s3.x += r3.x; s3.y += r3.y; s3.z += r3.z; s3.w += r3.w;
    }
    for (; t < Tf; ++t) {
        int i0 = cidx(csr[e0 + 4 * t + g]);
        float4 r0 = f16x4_to_f32(Xq[(size_t)i0 * 16]);
        s0.x += r0.x; s0.y += r0.y; s0.z += r0.z; s0.w += r0.w;
    }
    int rem = deg & 3;
    if (rem) {                  // one masked slot, streams g<rem valid
        int e = e0 + 4 * Tf + g;
        float m = (g < rem) ? 1.0f : 0.0f;
        int i0 = cidx(csr[(g < rem) ? e : (e1 - 1)]);
        float4 r0 = f16x4_to_f32(Xq[(size_t)i0 * 16]);
        s0.x += m * r0.x; s0.y += m * r0.y;
        s0.z += m * r0.z; s0.w += m * r0.w;
    }
    float4 s;
    s.x = (s0.x + s1.x) + (s2.x + s3.x);
    s.y = (s0.y + s1.y) + (s2.y + s3.y);
    s.z = (s0.z + s1.z) + (s2.z + s3.z);
    s.w = (s0.w + s1.w) + (s2.w + s3.w);
    float4 u = shfl_xor4(s, 16);
    s.x += u.x; s.y += u.y; s.z += u.z; s.w += u.w;
    u = shfl_xor4(s, 32);
    s.x += u.x; s.y += u.y; s.z += u.z; s.w += u.w;
    if (l < 16) {
        float inv = 1.0f / fmaxf((float)deg, 1.0f);
        f16x4 o = {(f16)(s.x * inv), (f16)(s.y * inv),
                   (f16)(s.z * inv), (f16)(s.w * inv)};
        *(f16x4*)&M16[(size_t)wid * NH + 4 * q] = o;
    }
}

// ---------- pass 4: node GEMM v8 — MFMA f16 (proven) ------------------------
__global__ __launch_bounds__(256) void node_gemm(
    const f16* __restrict__ X16, const f16* __restrict__ M16,
    const f16* __restrict__ wp, const float* __restrict__ bsage,
    float* __restrict__ A, f16* __restrict__ B16) {
    __shared__ f16 H16[64 * 64];
    const int T = threadIdx.x;
    const int l = T & 63, w = T >> 6;
    const int lr = l & 15, lg = l >> 4;
    const int nbase = blockIdx.x * 64;
    const int arow = w * 16 + lr;
    const int node = min(nbase + arow, NN - 1);
    const int kb = lg * 8;

    const f16x8* wv = (const f16x8*)wp;
    f16x8 xa0 = *(const f16x8*)&X16[(size_t)node * 64 + kb];
    f16x8 xa1 = *(const f16x8*)&X16[(size_t)node * 64 + 32 + kb];
    f16x8 ma0 = *(const f16x8*)&M16[(size_t)node * 64 + kb];
    f16x8 ma1 = *(const f16x8*)&M16[(size_t)node * 64 + 32 + kb];

    #pragma unroll
    for (int ct = 0; ct < 4; ++ct) {
        f16x8 ws0 = wv[(0 + ct) * 64 + l];
        f16x8 ws1 = wv[(4 + ct) * 64 + l];
        f16x8 wn0 = wv[(8 + ct) * 64 + l];
        f16x8 wn1 = wv[(12 + ct) * 64 + l];
        float bj = bsage[ct * 16 + lr];
        f32x4 acc = {bj, bj, bj, bj};
        acc = __builtin_amdgcn_mfma_f32_16x16x32_f16(xa0, ws0, acc, 0, 0, 0);
        acc = __builtin_amdgcn_mfma_f32_16x16x32_f16(xa1, ws1, acc, 0, 0, 0);
        acc = __builtin_amdgcn_mfma_f32_16x16x32_f16(ma0, wn0, acc, 0, 0, 0);
        acc = __builtin_amdgcn_mfma_f32_16x16x32_f16(ma1, wn1, acc, 0, 0, 0);
        #pragma unroll
        for (int i = 0; i < 4; ++i) {
            int rr = w * 16 + lg * 4 + i;
            int cc = ct * 16 + lr;
            H16[rr * 64 + ((((cc >> 3) ^ (rr & 7)) << 3) | (cc & 7))] =
                (f16)fmaxf(acc[i], 0.0f);
        }
    }
    __syncthreads();

    f16x8 ha0 = *(const f16x8*)
        &H16[arow * 64 + (((kb >> 3) ^ (arow & 7)) << 3)];
    f16x8 ha1 = *(const f16x8*)
        &H16[arow * 64 + ((((kb + 32) >> 3) ^ (arow & 7)) << 3)];
    #pragma unroll
    for (int ct = 0; ct < 4; ++ct) {
        f16x8 q10 = wv[(16 + ct) * 64 + l];
        f16x8 q11 = wv[(20 + ct) * 64 + l];
        f16x8 q20 = wv[(24 + ct) * 64 + l];
        f16x8 q21 = wv[(28 + ct) * 64 + l];
        f32x4 aA = {0.f, 0.f, 0.f, 0.f};
        f32x4 aB = {0.f, 0.f, 0.f, 0.f};
        aA = __builtin_amdgcn_mfma_f32_16x16x32_f16(ha0, q10, aA, 0, 0, 0);
        aA = __builtin_amdgcn_mfma_f32_16x16x32_f16(ha1, q11, aA, 0, 0, 0);
        aB = __builtin_amdgcn_mfma_f32_16x16x32_f16(ha0, q20, aB, 0, 0, 0);
        aB = __builtin_amdgcn_mfma_f32_16x16x32_f16(ha1, q21, aB, 0, 0, 0);
        #pragma unroll
        for (int i = 0; i < 4; ++i) {
            int gr = nbase + w * 16 + lg * 4 + i;
            if (gr < NN) {
                int cc = ct * 16 + lr;
                A[(size_t)gr * 64 + cc] = aA[i];
                B16[(size_t)gr * 64 + cc] = (f16)aB[i];
            }
        }
    }
}

// ---------- pass 5: edge_out, 16-lane-group rows (4 edges / load instr) -----
__global__ __launch_bounds__(256) void edge_out(
    const float* __restrict__ A, const f16* __restrict__ B16,
    const float* __restrict__ Qb, const int* __restrict__ off_src,
    const int* __restrict__ csr, float* __restrict__ out) {
    int wid = (int)(((long long)blockIdx.x * blockDim.x + threadIdx.x) >> 6);
    int l = threadIdx.x & 63;
    int q = l & 15, g = l >> 4;
    if (wid >= NN) return;
    float4 aq = *(const float4*)&A[(size_t)wid * NH + 4 * q];
    float4 qb = *(const float4*)&Qb[4 * q];
    aq.x += qb.x; aq.y += qb.y; aq.z += qb.z; aq.w += qb.w;
    int e0 = off_src[wid], e1 = off_src[wid + 1];
    int deg = e1 - e0;
    const f16x4* Bq = (const f16x4*)(B16 + 4 * q);
    float4 s0 = {0,0,0,0}, s1 = {0,0,0,0}, s2 = {0,0,0,0}, s3 = {0,0,0,0};
    int Tf = deg >> 2;
    int t = 0;
#define EACC(sv, rv)                                                   \
    { float4 tv;                                                       \
      tv.x = aq.x + rv.x; tv.y = aq.y + rv.y;                          \
      tv.z = aq.z + rv.z; tv.w = aq.w + rv.w;                          \
      sv.x += tv.x * tv.x; sv.y += tv.y * tv.y;                        \
      sv.z += tv.z * tv.z; sv.w += tv.w * tv.w; }
    for (; t + 4 <= Tf; t += 4) {
        int i0 = cidx(csr[e0 + 4 * (t + 0) + g]);
        int i1 = cidx(csr[e0 + 4 * (t + 1) + g]);
        int i2 = cidx(csr[e0 + 4 * (t + 2) + g]);
        int i3 = cidx(csr[e0 + 4 * (t + 3) + g]);
        float4 r0 = f16x4_to_f32(Bq[(size_t)i0 * 16]);
        float4 r1 = f16x4_to_f32(Bq[(size_t)i1 * 16]);
        float4 r2 = f16x4_to_f32(Bq[(size_t)i2 * 16]);
        float4 r3 = f16x4_to_f32(Bq[(size_t)i3 * 16]);
        EACC(s0, r0) EACC(s1, r1) EACC(s2, r2) EACC(s3, r3)
    }
    for (; t < Tf; ++t) {
        int i0 = cidx(csr[e0 + 4 * t + g]);
        float4 r0 = f16x4_to_f32(Bq[(size_t)i0 * 16]);
        EACC(s0, r0)
    }
    int rem = deg & 3;
    if (rem) {
        int e = e0 + 4 * Tf + g;
        float m = (g < rem) ? 1.0f : 0.0f;
        int i0 = cidx(csr[(g < rem) ? e : (e1 - 1)]);
        float4 r0 = f16x4_to_f32(Bq[(size_t)i0 * 16]);
        float4 tv;
        tv.x = aq.x + r0.x; tv.y = aq.y + r0.y;
        tv.z = aq.z + r0.z; tv.w = aq.w + r0.w;
        s0.x += m * tv.x * tv.x; s0.y += m * tv.y * tv.y;
        s0.z += m * tv.z * tv.z; s0.w += m * tv.w * tv.w;
    }
#undef EACC
    float4 s;
    s.x = (s0.x + s1.x) + (s2.x + s3.x);
    s.y = (s0.y + s1.y) + (s2.y + s3.y);
    s.z = (s0.z + s1.z) + (s2.z + s3.z);
    s.w = (s0.w + s1.w) + (s2.w + s3.w);
    float4 u = shfl_xor4(s, 16);
    s.x += u.x; s.y += u.y; s.z += u.z; s.w += u.w;
    u = shfl_xor4(s, 32);
    s.x += u.x; s.y += u.y; s.z += u.z; s.w += u.w;
    if (l < 16) {
        float inv = 1.0f / fmaxf((float)deg, 1.0f);
        float4 o;
        o.x = tanhf(s.x * inv); o.y = tanhf(s.y * inv);
        o.z = tanhf(s.z * inv); o.w = tanhf(s.w * inv);
        *(float4*)&out[(size_t)wid * NH + 4 * q] = o;
    }
}

extern "C" void kernel_launch(void* const* d_in, const int* in_sizes, int n_in,
                              void* d_out, int out_size, void* d_ws, size_t ws_size,
                              hipStream_t stream) {
    const float* X      = (const float*)d_in[0];
    const int*   ei     = (const int*)d_in[1];   // [2, NE] int32
    const float* Wself  = (const float*)d_in[2];
    const float* Wneigh = (const float*)d_in[3];
    const float* bsage  = (const float*)d_in[4];
    const float* Qw     = (const float*)d_in[5];
    const float* Qb     = (const float*)d_in[6];
    const int* src = ei;
    const int* dst = ei + NE;

    float* out = (float*)d_out;

    // workspace layout (~44 MB). M16 aliases pairs (pairs dead after sort).
    float* A   = (float*)d_ws;                       // NN*NH f32 (output A)
    f16* X16   = (f16*)(A + (size_t)NN * NH);        // NN*NH f16
    f16* B16   = X16 + (size_t)NN * NH;              // NN*NH f16
    unsigned* pairs = (unsigned*)(B16 + (size_t)NN * NH); // NBKT*CAP u32 (9.6MB)
    f16* M16   = (f16*)pairs;                        // aliases pairs (6.4MB)
    int* csr   = (int*)(pairs + (size_t)NBKT * CAP); // 2*NE
    int* off   = csr + 2 * NE;                       // NKEY+1
    int* gcnt  = off + NKEY + 1;                     // NBKT
    f16* wp    = (f16*)(gcnt + NBKT);                // 16384 f16 (32 KB)

    hipMemsetAsync(gcnt, 0, NBKT * sizeof(int), stream);

    bin_pass<<<BINB + PACKB, 256, 0, stream>>>(src, dst, gcnt, pairs,
                                               X, X16, Wself, Wneigh, Qw, wp);
    sort_pass<<<NBKT, 512, 0, stream>>>(pairs, gcnt, off, csr);
    gather_mean<<<(NN + 3) / 4, 256, 0, stream>>>(X16, off + NN, csr, M16);
    node_gemm<<<(NN + 63) / 64, 256, 0, stream>>>(X16, M16, wp, bsage, A, B16);
    edge_out<<<(NN + 3) / 4, 256, 0, stream>>>(A, B16, Qb, off, csr, out);
}

// Round 20
// 119.966 us; speedup vs baseline: 1.1082x; 1.1082x over previous
//
#include <hip/hip_runtime.h>
#include <math.h>

#define NN 50000
#define NE 1000000
#define NH 64
#define NKEY 100000      // 2*NN combined key space (src | NN+dst)
#define SPAN 512         // keys per bucket
#define NBKT 196         // ceil(NKEY / SPAN)
#define CAP 12288        // bucket capacity (mean 10240, generous)
#define CH 32            // LDS staging entries per bucket (pow2 for shift math)
#define BINB 512         // bin-duty blocks in bin_pass (proven at 512)
#define PACKB 256        // pack-duty blocks in bin_pass

typedef _Float16 f16;
typedef _Float16 f16x4 __attribute__((ext_vector_type(4)));
typedef _Float16 f16x8 __attribute__((ext_vector_type(8)));
typedef float f32x4 __attribute__((ext_vector_type(4)));

// ---------- binning helpers -------------------------------------------------
__device__ __forceinline__ void push_pair(int key, int val, int* cnt,
                                          unsigned* buf, int* gcnt,
                                          unsigned* __restrict__ pairs) {
    int b = key >> 9;
    unsigned pk = ((unsigned)val << 9) | (unsigned)(key & 511);
    int slot = atomicAdd(&cnt[b], 1);           // LDS atomic
    if (slot < CH) {
        buf[b * CH + slot] = pk;
    } else {                                     // rare overflow: direct path
        int g = atomicAdd(&gcnt[b], 1);
        if (g < CAP) pairs[(size_t)b * CAP + g] = pk;
    }
}

__device__ __forceinline__ void flush_coop(int* cnt, int* s_fc, int* s_g,
                                           unsigned* buf, int* gcnt,
                                           unsigned* __restrict__ pairs) {
    __syncthreads();
    int t = threadIdx.x;
    if (t < NBKT) {
        int fc = cnt[t]; if (fc > CH) fc = CH;
        s_fc[t] = fc;
        s_g[t] = (fc > 0) ? atomicAdd(&gcnt[t], fc) : 0;
    }
    __syncthreads();
    for (int i = t; i < NBKT * CH; i += 256) {
        int b = i >> 5, s = i & 31;              // CH == 32
        if (s < s_fc[b])
            pairs[(size_t)b * CAP + s_g[b] + s] = buf[i];
    }
    __syncthreads();
    if (t < NBKT) cnt[t] = 0;
    __syncthreads();
}

// ---------- pass 1: bin 2M (key,val) pairs; extra blocks do f16/weight pack -
__global__ __launch_bounds__(256) void bin_pass(
    const int* __restrict__ src, const int* __restrict__ dst,
    int* __restrict__ gcnt, unsigned* __restrict__ pairs,
    const float* __restrict__ X, f16* __restrict__ X16,
    const float* __restrict__ Ws, const float* __restrict__ Wn,
    const float* __restrict__ Qw, f16* __restrict__ wp) {
    if (blockIdx.x >= BINB) {
        // ---- pack duty: X -> f16 table, weights -> fragment-packed f16 ----
        int start = (blockIdx.x - BINB) * 256 + threadIdx.x;
        for (int i = start; i < NN * NH / 4; i += PACKB * 256) {
            float4 v = ((const float4*)X)[i];
            f16x4 o = {(f16)v.x, (f16)v.y, (f16)v.z, (f16)v.w};
            ((f16x4*)X16)[i] = o;
        }
        for (int i = start; i < 16384; i += PACKB * 256) {
            int m  = i >> 12;
            int kc = (i >> 11) & 1;
            int l  = (i >> 3) & 63;
            int e  = i & 7;
            int ct = (i >> 9) & 3;
            int k  = kc * 32 + (l >> 4) * 8 + e;
            int j  = ct * 16 + (l & 15);
            const float* W = (m == 0) ? Ws : (m == 1) ? Wn : (m == 2) ? Qw
                                                          : (Qw + 4096);
            wp[i] = (f16)W[k * 64 + j];
        }
        return;
    }
    __shared__ int cnt[NBKT];
    __shared__ int s_fc[NBKT];
    __shared__ int s_g[NBKT];
    __shared__ unsigned buf[NBKT * CH];
    for (int b = threadIdx.x; b < NBKT; b += 256) cnt[b] = 0;
    __syncthreads();
    int r = 0;
    for (int base = blockIdx.x * 256; base < NE; base += BINB * 256) {
        int e = base + threadIdx.x;
        if (e < NE) {
            int s = src[e], d = dst[e];
            push_pair(s, d, cnt, buf, gcnt, pairs);       // out-edge of s
            push_pair(NN + d, s, cnt, buf, gcnt, pairs);  // in-edge of d
        }
        if ((++r & 7) == 0) flush_coop(cnt, s_fc, s_g, buf, gcnt, pairs);
    }
    flush_coop(cnt, s_fc, s_g, buf, gcnt, pairs);
}

// ---------- pass 2: per-bucket counting sort + off/csr (scan folded in) -----
__global__ __launch_bounds__(1024) void sort_pass(
    const unsigned* __restrict__ pairs, const int* __restrict__ gcnt,
    int* __restrict__ off, int* __restrict__ csr) {
    __shared__ int hist[SPAN];
    __shared__ int scn[SPAN];
    __shared__ int bsc[256];
    int k = blockIdx.x;
    int t = threadIdx.x;

    if (t < 256) bsc[t] = (t < NBKT) ? gcnt[t] : 0;
    __syncthreads();
    for (int o = 1; o < 256; o <<= 1) {
        int u = 0;
        if (t < 256 && t >= o) u = bsc[t - o];
        __syncthreads();
        if (t < 256) bsc[t] += u;
        __syncthreads();
    }
    int base = (k > 0) ? bsc[k - 1] : 0;
    int n = gcnt[k]; if (n > CAP) n = CAP;
    const unsigned* bp = pairs + (size_t)k * CAP;
    if (k == 0 && t == 0) off[NKEY] = 2 * NE;    // sentinel

    if (t < SPAN) hist[t] = 0;
    __syncthreads();
    for (int i = t; i < n; i += 1024)
        atomicAdd(&hist[bp[i] & 511], 1);
    __syncthreads();
    if (t < SPAN) scn[t] = hist[t];
    __syncthreads();
    for (int o = 1; o < SPAN; o <<= 1) {
        int u = 0;
        if (t < SPAN && t >= o) u = scn[t - o];
        __syncthreads();
        if (t < SPAN) scn[t] += u;
        __syncthreads();
    }
    if (t < SPAN) {
        int ex = base + scn[t] - hist[t];   // absolute exclusive prefix
        int gk = k * SPAN + t;
        if (gk < NKEY) off[gk] = ex;
        scn[t] = ex;                        // reuse as cursor
    }
    __syncthreads();
    for (int i = t; i < n; i += 1024) {
        unsigned p = bp[i];
        int pos = atomicAdd(&scn[p & 511], 1);   // LDS atomic
        csr[pos] = (int)(p >> 9);                // block-local global store
    }
}

// clamp gathered index (protects rocprof dispatch-replay from stale buffers)
__device__ __forceinline__ int cidx(int i) {
    return max(0, min(i, NN - 1));
}

__device__ __forceinline__ float4 f16x4_to_f32(f16x4 r) {
    float4 o; o.x = (float)r.x; o.y = (float)r.y;
    o.z = (float)r.z; o.w = (float)r.w; return o;
}
__device__ __forceinline__ float4 shfl_xor4(float4 v, int m) {
    float4 o;
    o.x = __shfl_xor(v.x, m, 64); o.y = __shfl_xor(v.y, m, 64);
    o.z = __shfl_xor(v.z, m, 64); o.w = __shfl_xor(v.w, m, 64);
    return o;
}

// ---------- pass 3: gather-mean, 16-lane-group rows (4 edges / load instr) --
// wave = node; lane l: cols 4q..4q+3 (q=l&15) of edge-stream g=l>>4.
__global__ __launch_bounds__(256) void gather_mean(
    const f16* __restrict__ X16, const int* __restrict__ off_dst,
    const int* __restrict__ csr, f16* __restrict__ M16) {
    int wid = (int)(((long long)blockIdx.x * blockDim.x + threadIdx.x) >> 6);
    int l = threadIdx.x & 63;
    int q = l & 15, g = l >> 4;
    if (wid >= NN) return;
    int e0 = off_dst[wid], e1 = off_dst[wid + 1];
    int deg = e1 - e0;
    const f16x4* Xq = (const f16x4*)(X16 + 4 * q);   // row base + col offset
    float4 s0 = {0,0,0,0}, s1 = {0,0,0,0}, s2 = {0,0,0,0}, s3 = {0,0,0,0};
    int Tf = deg >> 2;          // fully-valid slots (all 4 streams)
    int t = 0;
    for (; t + 4 <= Tf; t += 4) {
        int i0 = cidx(csr[e0 + 4 * (t + 0) + g]);
        int i1 = cidx(csr[e0 + 4 * (t + 1) + g]);
        int i2 = cidx(csr[e0 + 4 * (t + 2) + g]);
        int i3 = cidx(csr[e0 + 4 * (t + 3) + g]);
        float4 r0 = f16x4_to_f32(Xq[(size_t)i0 * 16]);
        float4 r1 = f16x4_to_f32(Xq[(size_t)i1 * 16]);
        float4 r2 = f16x4_to_f32(Xq[(size_t)i2 * 16]);
        float4 r3 = f16x4_to_f32(Xq[(size_t)i3 * 16]);
        s0.x += r0.x; s0.y += r0.y; s0.z += r0.z; s0.w += r0.w;
        s1.x += r1.x; s1.y += r1.y; s1.z += r1.z; s1.w += r1.w;
        s2.x += r2.x; s2.y += r2.y; s2.z += r2.z; s2.w += r2.w;
        s3.x += r3.x; s3.y += r3.y; s3.z += r3.z; s3.w += r3.w;
    }
    for (; t < Tf; ++t) {
        int i0 = cidx(csr[e0 + 4 * t + g]);
        float4 r0 = f16x4_to_f32(Xq[(size_t)i0 * 16]);
        s0.x += r0.x; s0.y += r0.y; s0.z += r0.z; s0.w += r0.w;
    }
    int rem = deg & 3;
    if (rem) {                  // one masked slot, streams g<rem valid
        int e = e0 + 4 * Tf + g;
        float m = (g < rem) ? 1.0f : 0.0f;
        int i0 = cidx(csr[(g < rem) ? e : (e1 - 1)]);
        float4 r0 = f16x4_to_f32(Xq[(size_t)i0 * 16]);
        s0.x += m * r0.x; s0.y += m * r0.y;
        s0.z += m * r0.z; s0.w += m * r0.w;
    }
    float4 s;
    s.x = (s0.x + s1.x) + (s2.x + s3.x);
    s.y = (s0.y + s1.y) + (s2.y + s3.y);
    s.z = (s0.z + s1.z) + (s2.z + s3.z);
    s.w = (s0.w + s1.w) + (s2.w + s3.w);
    float4 u = shfl_xor4(s, 16);
    s.x += u.x; s.y += u.y; s.z += u.z; s.w += u.w;
    u = shfl_xor4(s, 32);
    s.x += u.x; s.y += u.y; s.z += u.z; s.w += u.w;
    if (l < 16) {
        float inv = 1.0f / fmaxf((float)deg, 1.0f);
        f16x4 o = {(f16)(s.x * inv), (f16)(s.y * inv),
                   (f16)(s.z * inv), (f16)(s.w * inv)};
        *(f16x4*)&M16[(size_t)wid * NH + 4 * q] = o;
    }
}

// ---------- pass 4: node GEMM v8 — MFMA f16 (proven) ------------------------
__global__ __launch_bounds__(256) void node_gemm(
    const f16* __restrict__ X16, const f16* __restrict__ M16,
    const f16* __restrict__ wp, const float* __restrict__ bsage,
    float* __restrict__ A, f16* __restrict__ B16) {
    __shared__ f16 H16[64 * 64];
    const int T = threadIdx.x;
    const int l = T & 63, w = T >> 6;
    const int lr = l & 15, lg = l >> 4;
    const int nbase = blockIdx.x * 64;
    const int arow = w * 16 + lr;
    const int node = min(nbase + arow, NN - 1);
    const int kb = lg * 8;

    const f16x8* wv = (const f16x8*)wp;
    f16x8 xa0 = *(const f16x8*)&X16[(size_t)node * 64 + kb];
    f16x8 xa1 = *(const f16x8*)&X16[(size_t)node * 64 + 32 + kb];
    f16x8 ma0 = *(const f16x8*)&M16[(size_t)node * 64 + kb];
    f16x8 ma1 = *(const f16x8*)&M16[(size_t)node * 64 + 32 + kb];

    #pragma unroll
    for (int ct = 0; ct < 4; ++ct) {
        f16x8 ws0 = wv[(0 + ct) * 64 + l];
        f16x8 ws1 = wv[(4 + ct) * 64 + l];
        f16x8 wn0 = wv[(8 + ct) * 64 + l];
        f16x8 wn1 = wv[(12 + ct) * 64 + l];
        float bj = bsage[ct * 16 + lr];
        f32x4 acc = {bj, bj, bj, bj};
        acc = __builtin_amdgcn_mfma_f32_16x16x32_f16(xa0, ws0, acc, 0, 0, 0);
        acc = __builtin_amdgcn_mfma_f32_16x16x32_f16(xa1, ws1, acc, 0, 0, 0);
        acc = __builtin_amdgcn_mfma_f32_16x16x32_f16(ma0, wn0, acc, 0, 0, 0);
        acc = __builtin_amdgcn_mfma_f32_16x16x32_f16(ma1, wn1, acc, 0, 0, 0);
        #pragma unroll
        for (int i = 0; i < 4; ++i) {
            int rr = w * 16 + lg * 4 + i;
            int cc = ct * 16 + lr;
            H16[rr * 64 + ((((cc >> 3) ^ (rr & 7)) << 3) | (cc & 7))] =
                (f16)fmaxf(acc[i], 0.0f);
        }
    }
    __syncthreads();

    f16x8 ha0 = *(const f16x8*)
        &H16[arow * 64 + (((kb >> 3) ^ (arow & 7)) << 3)];
    f16x8 ha1 = *(const f16x8*)
        &H16[arow * 64 + ((((kb + 32) >> 3) ^ (arow & 7)) << 3)];
    #pragma unroll
    for (int ct = 0; ct < 4; ++ct) {
        f16x8 q10 = wv[(16 + ct) * 64 + l];
        f16x8 q11 = wv[(20 + ct) * 64 + l];
        f16x8 q20 = wv[(24 + ct) * 64 + l];
        f16x8 q21 = wv[(28 + ct) * 64 + l];
        f32x4 aA = {0.f, 0.f, 0.f, 0.f};
        f32x4 aB = {0.f, 0.f, 0.f, 0.f};
        aA = __builtin_amdgcn_mfma_f32_16x16x32_f16(ha0, q10, aA, 0, 0, 0);
        aA = __builtin_amdgcn_mfma_f32_16x16x32_f16(ha1, q11, aA, 0, 0, 0);
        aB = __builtin_amdgcn_mfma_f32_16x16x32_f16(ha0, q20, aB, 0, 0, 0);
        aB = __builtin_amdgcn_mfma_f32_16x16x32_f16(ha1, q21, aB, 0, 0, 0);
        #pragma unroll
        for (int i = 0; i < 4; ++i) {
            int gr = nbase + w * 16 + lg * 4 + i;
            if (gr < NN) {
                int cc = ct * 16 + lr;
                A[(size_t)gr * 64 + cc] = aA[i];
                B16[(size_t)gr * 64 + cc] = (f16)aB[i];
            }
        }
    }
}

// ---------- pass 5: edge_out, 16-lane-group rows (4 edges / load instr) -----
__global__ __launch_bounds__(256) void edge_out(
    const float* __restrict__ A, const f16* __restrict__ B16,
    const float* __restrict__ Qb, const int* __restrict__ off_src,
    const int* __restrict__ csr, float* __restrict__ out) {
    int wid = (int)(((long long)blockIdx.x * blockDim.x + threadIdx.x) >> 6);
    int l = threadIdx.x & 63;
    int q = l & 15, g = l >> 4;
    if (wid >= NN) return;
    float4 aq = *(const float4*)&A[(size_t)wid * NH + 4 * q];
    float4 qb = *(const float4*)&Qb[4 * q];
    aq.x += qb.x; aq.y += qb.y; aq.z += qb.z; aq.w += qb.w;
    int e0 = off_src[wid], e1 = off_src[wid + 1];
    int deg = e1 - e0;
    const f16x4* Bq = (const f16x4*)(B16 + 4 * q);
    float4 s0 = {0,0,0,0}, s1 = {0,0,0,0}, s2 = {0,0,0,0}, s3 = {0,0,0,0};
    int Tf = deg >> 2;
    int t = 0;
#define EACC(sv, rv)                                                   \
    { float4 tv;                                                       \
      tv.x = aq.x + rv.x; tv.y = aq.y + rv.y;                          \
      tv.z = aq.z + rv.z; tv.w = aq.w + rv.w;                          \
      sv.x += tv.x * tv.x; sv.y += tv.y * tv.y;                        \
      sv.z += tv.z * tv.z; sv.w += tv.w * tv.w; }
    for (; t + 4 <= Tf; t += 4) {
        int i0 = cidx(csr[e0 + 4 * (t + 0) + g]);
        int i1 = cidx(csr[e0 + 4 * (t + 1) + g]);
        int i2 = cidx(csr[e0 + 4 * (t + 2) + g]);
        int i3 = cidx(csr[e0 + 4 * (t + 3) + g]);
        float4 r0 = f16x4_to_f32(Bq[(size_t)i0 * 16]);
        float4 r1 = f16x4_to_f32(Bq[(size_t)i1 * 16]);
        float4 r2 = f16x4_to_f32(Bq[(size_t)i2 * 16]);
        float4 r3 = f16x4_to_f32(Bq[(size_t)i3 * 16]);
        EACC(s0, r0) EACC(s1, r1) EACC(s2, r2) EACC(s3, r3)
    }
    for (; t < Tf; ++t) {
        int i0 = cidx(csr[e0 + 4 * t + g]);
        float4 r0 = f16x4_to_f32(Bq[(size_t)i0 * 16]);
        EACC(s0, r0)
    }
    int rem = deg & 3;
    if (rem) {
        int e = e0 + 4 * Tf + g;
        float m = (g < rem) ? 1.0f : 0.0f;
        int i0 = cidx(csr[(g < rem) ? e : (e1 - 1)]);
        float4 r0 = f16x4_to_f32(Bq[(size_t)i0 * 16]);
        float4 tv;
        tv.x = aq.x + r0.x; tv.y = aq.y + r0.y;
        tv.z = aq.z + r0.z; tv.w = aq.w + r0.w;
        s0.x += m * tv.x * tv.x; s0.y += m * tv.y * tv.y;
        s0.z += m * tv.z * tv.z; s0.w += m * tv.w * tv.w;
    }
#undef EACC
    float4 s;
    s.x = (s0.x + s1.x) + (s2.x + s3.x);
    s.y = (s0.y + s1.y) + (s2.y + s3.y);
    s.z = (s0.z + s1.z) + (s2.z + s3.z);
    s.w = (s0.w + s1.w) + (s2.w + s3.w);
    float4 u = shfl_xor4(s, 16);
    s.x += u.x; s.y += u.y; s.z += u.z; s.w += u.w;
    u = shfl_xor4(s, 32);
    s.x += u.x; s.y += u.y; s.z += u.z; s.w += u.w;
    if (l < 16) {
        float inv = 1.0f / fmaxf((float)deg, 1.0f);
        float4 o;
        o.x = tanhf(s.x * inv); o.y = tanhf(s.y * inv);
        o.z = tanhf(s.z * inv); o.w = tanhf(s.w * inv);
        *(float4*)&out[(size_t)wid * NH + 4 * q] = o;
    }
}

extern "C" void kernel_launch(void* const* d_in, const int* in_sizes, int n_in,
                              void* d_out, int out_size, void* d_ws, size_t ws_size,
                              hipStream_t stream) {
    const float* X      = (const float*)d_in[0];
    const int*   ei     = (const int*)d_in[1];   // [2, NE] int32
    const float* Wself  = (const float*)d_in[2];
    const float* Wneigh = (const float*)d_in[3];
    const float* bsage  = (const float*)d_in[4];
    const float* Qw     = (const float*)d_in[5];
    const float* Qb     = (const float*)d_in[6];
    const int* src = ei;
    const int* dst = ei + NE;

    float* out = (float*)d_out;

    // workspace layout (~44 MB). M16 aliases pairs (pairs dead after sort).
    float* A   = (float*)d_ws;                       // NN*NH f32 (output A)
    f16* X16   = (f16*)(A + (size_t)NN * NH);        // NN*NH f16
    f16* B16   = X16 + (size_t)NN * NH;              // NN*NH f16
    unsigned* pairs = (unsigned*)(B16 + (size_t)NN * NH); // NBKT*CAP u32
    f16* M16   = (f16*)pairs;                        // aliases pairs
    int* csr   = (int*)(pairs + (size_t)NBKT * CAP); // 2*NE
    int* off   = csr + 2 * NE;                       // NKEY+1
    int* gcnt  = off + NKEY + 1;                     // NBKT
    f16* wp    = (f16*)(gcnt + NBKT);                // 16384 f16 (32 KB)

    hipMemsetAsync(gcnt, 0, NBKT * sizeof(int), stream);

    bin_pass<<<BINB + PACKB, 256, 0, stream>>>(src, dst, gcnt, pairs,
                                               X, X16, Wself, Wneigh, Qw, wp);
    sort_pass<<<NBKT, 1024, 0, stream>>>(pairs, gcnt, off, csr);
    gather_mean<<<(NN + 3) / 4, 256, 0, stream>>>(X16, off + NN, csr, M16);
    node_gemm<<<(NN + 63) / 64, 256, 0, stream>>>(X16, M16, wp, bsage, A, B16);
    edge_out<<<(NN + 3) / 4, 256, 0, stream>>>(A, B16, Qb, off, csr, out);
}